// Round 1
// baseline (824.850 us; speedup 1.0000x reference)
//
#include <hip/hip_runtime.h>

#define N_NODES 100000
#define FEAT_IN 512
#define C1 16
#define C2 32
#define NEDGE 3200000
#define B_DDI 4096
#define F_DDI 1056

// workspace offsets (bytes), all 16B-aligned
#define O_CNT    0u          // N ints   (degree counts, later CSR fill cursor)
#define O_DINV   524288u     // N floats (rsqrt(deg+1))
#define O_ROWPTR 1048576u    // N+1 ints
#define O_COL    1572864u    // E ints   (CSR src indices)
#define O_H1     14680064u   // N*16 floats
#define O_OUT1   22020096u   // N*16 floats
#define O_H2     28835840u   // N*32 floats
#define O_BSUM   41943040u   // scan block sums (196 ints)

// ---------------- CSR build ----------------

__global__ void k_count(const int* __restrict__ ei, int* __restrict__ cnt) {
    int e = blockIdx.x * blockDim.x + threadIdx.x;
    if (e < NEDGE) atomicAdd(&cnt[ei[NEDGE + e]], 1);
}

__global__ void k_dinv(const int* __restrict__ cnt, float* __restrict__ dinv) {
    int i = blockIdx.x * blockDim.x + threadIdx.x;
    if (i < N_NODES) dinv[i] = rsqrtf((float)cnt[i] + 1.0f);
}

__global__ void k_scan1(const int* __restrict__ cnt, int* __restrict__ rp, int* __restrict__ bsum) {
    __shared__ int s[512];
    int tid = threadIdx.x;
    int i = blockIdx.x * 512 + tid;
    int v = (i < N_NODES) ? cnt[i] : 0;
    s[tid] = v;
    __syncthreads();
    for (int off = 1; off < 512; off <<= 1) {
        int t = (tid >= off) ? s[tid - off] : 0;
        __syncthreads();
        s[tid] += t;
        __syncthreads();
    }
    if (i < N_NODES) rp[i] = s[tid] - v;   // exclusive within block
    if (tid == 511) bsum[blockIdx.x] = s[511];
}

#define NB_SCAN 196
__global__ void k_scan2(int* __restrict__ bsum) {
    __shared__ int s[256];
    int tid = threadIdx.x;
    int v = (tid < NB_SCAN) ? bsum[tid] : 0;
    s[tid] = v;
    __syncthreads();
    for (int off = 1; off < 256; off <<= 1) {
        int t = (tid >= off) ? s[tid - off] : 0;
        __syncthreads();
        s[tid] += t;
        __syncthreads();
    }
    if (tid < NB_SCAN) bsum[tid] = s[tid] - v;  // exclusive block offsets
}

__global__ void k_scan3(int* __restrict__ rp, const int* __restrict__ bsum, int* __restrict__ cursor) {
    int i = blockIdx.x * 512 + threadIdx.x;
    if (i < N_NODES) {
        int v = rp[i] + bsum[blockIdx.x];
        rp[i] = v;
        cursor[i] = v;   // fill cursor starts at row begin
    }
    if (i == 0) rp[N_NODES] = NEDGE;
}

__global__ void k_fill(const int* __restrict__ ei, int* __restrict__ cursor, int* __restrict__ col) {
    int e = blockIdx.x * blockDim.x + threadIdx.x;
    if (e < NEDGE) {
        int s = ei[e];
        int d = ei[NEDGE + e];
        int p = atomicAdd(&cursor[d], 1);
        col[p] = s;
    }
}

// ---------------- GEMM1: h1 = x @ W1  [100000x512]x[512x16] ----------------

#define G1_ROWS 256
#define G1_KC 32
#define XS_PAD 260   // 256 rows + pad, keeps ds_read_b128 ~2-way

__global__ __launch_bounds__(256) void k_gemm1(const float* __restrict__ x,
                                               const float* __restrict__ W1,
                                               float* __restrict__ h1) {
    __shared__ float xs[G1_KC][XS_PAD];  // transposed: [k][row]
    __shared__ float ws[G1_KC][16];      // [k][c]
    int tid = threadIdx.x;
    int r0 = blockIdx.x * G1_ROWS;
    int rg = tid >> 2;   // 0..63 : 4 rows each
    int cg = tid & 3;    // 0..3  : 4 cols each
    float acc[4][4] = {{0.f}};

    for (int k0 = 0; k0 < FEAT_IN; k0 += G1_KC) {
        __syncthreads();
        // stage x tile: 256 rows x 32 k, each thread 8 float4, written transposed
        #pragma unroll
        for (int jj = 0; jj < 8; ++jj) {
            int linear = tid + jj * 256;      // float4 index 0..2047
            int row = linear >> 3;            // 8 float4 per row
            int kq  = linear & 7;
            float4 xv = make_float4(0.f, 0.f, 0.f, 0.f);
            if (r0 + row < N_NODES)
                xv = *reinterpret_cast<const float4*>(&x[(size_t)(r0 + row) * FEAT_IN + k0 + kq * 4]);
            xs[kq * 4 + 0][row] = xv.x;
            xs[kq * 4 + 1][row] = xv.y;
            xs[kq * 4 + 2][row] = xv.z;
            xs[kq * 4 + 3][row] = xv.w;
        }
        // stage W tile: 32x16 = 128 float4
        if (tid < 128) {
            float4 wv = *reinterpret_cast<const float4*>(&W1[k0 * 16 + tid * 4]);
            *reinterpret_cast<float4*>(&ws[0][0] + tid * 4) = wv;
        }
        __syncthreads();
        #pragma unroll
        for (int k = 0; k < G1_KC; ++k) {
            float4 xv = *reinterpret_cast<const float4*>(&xs[k][rg * 4]);
            float4 wv = *reinterpret_cast<const float4*>(&ws[k][cg * 4]);
            float xa[4] = {xv.x, xv.y, xv.z, xv.w};
            float wa[4] = {wv.x, wv.y, wv.z, wv.w};
            #pragma unroll
            for (int i = 0; i < 4; ++i)
                #pragma unroll
                for (int j = 0; j < 4; ++j)
                    acc[i][j] += xa[i] * wa[j];
        }
    }
    #pragma unroll
    for (int i = 0; i < 4; ++i) {
        int row = r0 + rg * 4 + i;
        if (row < N_NODES) {
            float4 o = make_float4(acc[i][0], acc[i][1], acc[i][2], acc[i][3]);
            *reinterpret_cast<float4*>(&h1[row * C1 + cg * 4]) = o;
        }
    }
}

// ---------------- gather layer 1 (fused norm+selfloop+bias+relu) ----------------

__global__ __launch_bounds__(256) void k_gather1(const int* __restrict__ rp, const int* __restrict__ col,
                                                 const float* __restrict__ dinv, const float* __restrict__ h1,
                                                 const float* __restrict__ b1, float* __restrict__ out1) {
    int t = blockIdx.x * 256 + threadIdx.x;
    int node = t >> 4;
    int c = t & 15;
    int beg = rp[node], end = rp[node + 1];
    float di = dinv[node];
    float acc = 0.f;
    for (int p = beg; p < end; ++p) {
        int s = col[p];
        acc += dinv[s] * h1[s * C1 + c];
    }
    float v = di * acc + h1[node * C1 + c] * (di * di) + b1[c];
    out1[node * C1 + c] = fmaxf(v, 0.0f);
}

// ---------------- GEMM2: h2 = out1 @ W2  [100000x16]x[16x32] ----------------

__global__ __launch_bounds__(256) void k_gemm2(const float* __restrict__ in,
                                               const float* __restrict__ W2,
                                               float* __restrict__ h2) {
    __shared__ float ws[16 * 32];
    int tid = threadIdx.x;
    if (tid < 128) {
        float4 wv = *reinterpret_cast<const float4*>(&W2[tid * 4]);
        *reinterpret_cast<float4*>(&ws[tid * 4]) = wv;
    }
    __syncthreads();
    int t = blockIdx.x * 256 + tid;
    int node = t >> 5;
    int c = t & 31;
    const float4* rowp = reinterpret_cast<const float4*>(&in[node * C1]);
    float4 a = rowp[0], b = rowp[1], cc = rowp[2], d = rowp[3];
    float rv[16] = {a.x, a.y, a.z, a.w, b.x, b.y, b.z, b.w,
                    cc.x, cc.y, cc.z, cc.w, d.x, d.y, d.z, d.w};
    float acc = 0.f;
    #pragma unroll
    for (int k = 0; k < 16; ++k) acc += rv[k] * ws[k * 32 + c];
    h2[node * C2 + c] = acc;
}

// ---------------- gather layer 2 -> d_out (ppi) ----------------

__global__ __launch_bounds__(256) void k_gather2(const int* __restrict__ rp, const int* __restrict__ col,
                                                 const float* __restrict__ dinv, const float* __restrict__ h2,
                                                 const float* __restrict__ b2, float* __restrict__ out) {
    int t = blockIdx.x * 256 + threadIdx.x;
    int node = t >> 5;
    int c = t & 31;
    int beg = rp[node], end = rp[node + 1];
    float di = dinv[node];
    float acc = 0.f;
    for (int p = beg; p < end; ++p) {
        int s = col[p];
        acc += dinv[s] * h2[s * C2 + c];
    }
    float v = di * acc + h2[node * C2 + c] * (di * di) + b2[c];
    out[node * C2 + c] = fmaxf(v, 0.0f);
}

// ---------------- DDI branch: fc1+relu -> fc2+relu -> fc3+relu ----------------

#define DDI_CHUNK 132   // 1056 = 8 * 132

__global__ __launch_bounds__(256) void k_ddi(const float* __restrict__ feat,
                                             const float* __restrict__ fW1, const float* __restrict__ fb1,
                                             const float* __restrict__ fW2, const float* __restrict__ fb2,
                                             const float* __restrict__ fW3, const float* __restrict__ fb3,
                                             float* __restrict__ out) {
    __shared__ float sW[DDI_CHUNK * 64];
    __shared__ float sH[4][64];
    int tid = threadIdx.x;
    int wave = tid >> 6;
    int lane = tid & 63;
    int row = blockIdx.x * 4 + wave;

    float acc = 0.f;
    for (int k0 = 0; k0 < F_DDI; k0 += DDI_CHUNK) {
        __syncthreads();
        for (int idx = tid; idx < DDI_CHUNK * 64; idx += 256)
            sW[idx] = fW1[k0 * 64 + idx];
        __syncthreads();
        const float* frow = &feat[(size_t)row * F_DDI + k0];
        #pragma unroll 4
        for (int kk = 0; kk < DDI_CHUNK; kk += 4) {
            float4 fv = *reinterpret_cast<const float4*>(&frow[kk]);
            acc += fv.x * sW[(kk + 0) * 64 + lane];
            acc += fv.y * sW[(kk + 1) * 64 + lane];
            acc += fv.z * sW[(kk + 2) * 64 + lane];
            acc += fv.w * sW[(kk + 3) * 64 + lane];
        }
    }
    float h = fmaxf(acc + fb1[lane], 0.f);
    __syncthreads();
    sH[wave][lane] = h;
    __syncthreads();

    int c16 = lane & 15;
    float acc2 = 0.f;
    #pragma unroll
    for (int kk = 0; kk < 64; ++kk)
        acc2 += sH[wave][kk] * fW2[kk * 16 + c16];
    float o2 = fmaxf(acc2 + fb2[c16], 0.f);
    float part = o2 * fW3[c16];
    #pragma unroll
    for (int off = 8; off >= 1; off >>= 1)
        part += __shfl_xor(part, off, 16);
    if (lane == 0)
        out[row] = fmaxf(part + fb3[0], 0.f);
}

// ---------------- launch ----------------

extern "C" void kernel_launch(void* const* d_in, const int* in_sizes, int n_in,
                              void* d_out, int out_size, void* d_ws, size_t ws_size,
                              hipStream_t stream) {
    const float* x   = (const float*)d_in[0];
    const int*   ei  = (const int*)d_in[1];
    const float* ddi = (const float*)d_in[2];
    const float* W1  = (const float*)d_in[3];
    const float* b1  = (const float*)d_in[4];
    const float* W2  = (const float*)d_in[5];
    const float* b2  = (const float*)d_in[6];
    const float* fW1 = (const float*)d_in[7];
    const float* fb1 = (const float*)d_in[8];
    const float* fW2 = (const float*)d_in[9];
    const float* fb2 = (const float*)d_in[10];
    const float* fW3 = (const float*)d_in[11];
    const float* fb3 = (const float*)d_in[12];

    char* ws = (char*)d_ws;
    int*   cnt   = (int*)(ws + O_CNT);
    float* dinv  = (float*)(ws + O_DINV);
    int*   rp    = (int*)(ws + O_ROWPTR);
    int*   col   = (int*)(ws + O_COL);
    float* h1    = (float*)(ws + O_H1);
    float* out1  = (float*)(ws + O_OUT1);
    float* h2    = (float*)(ws + O_H2);
    int*   bsum  = (int*)(ws + O_BSUM);

    float* out_ppi = (float*)d_out;
    float* out_ddi = out_ppi + (size_t)N_NODES * C2;

    hipMemsetAsync(cnt, 0, N_NODES * sizeof(int), stream);
    k_count<<<NEDGE / 256, 256, 0, stream>>>(ei, cnt);
    k_dinv<<<(N_NODES + 255) / 256, 256, 0, stream>>>(cnt, dinv);
    k_scan1<<<NB_SCAN, 512, 0, stream>>>(cnt, rp, bsum);
    k_scan2<<<1, 256, 0, stream>>>(bsum);
    k_scan3<<<NB_SCAN, 512, 0, stream>>>(rp, bsum, cnt);
    k_fill<<<NEDGE / 256, 256, 0, stream>>>(ei, cnt, col);

    k_gemm1<<<(N_NODES + G1_ROWS - 1) / G1_ROWS, 256, 0, stream>>>(x, W1, h1);
    k_gather1<<<N_NODES * C1 / 256, 256, 0, stream>>>(rp, col, dinv, h1, b1, out1);
    k_gemm2<<<N_NODES * C2 / 256, 256, 0, stream>>>(out1, W2, h2);
    k_gather2<<<N_NODES * C2 / 256, 256, 0, stream>>>(rp, col, dinv, h2, b2, out_ppi);

    k_ddi<<<B_DDI / 4, 256, 0, stream>>>(ddi, fW1, fb1, fW2, fb2, fW3, fb3, out_ddi);
}

// Round 2
// 646.573 us; speedup vs baseline: 1.2757x; 1.2757x over previous
//
#include <hip/hip_runtime.h>

#define N_NODES 100000
#define FEAT_IN 512
#define C1 16
#define C2 32
#define NEDGE 3200000
#define B_DDI 4096
#define F_DDI 1056

#define NBUCK 196          // 512-node dst buckets
#define BIN_C 12288        // edges per k_bin block chunk
#define NB_BIN ((NEDGE + BIN_C - 1) / BIN_C)   // 261
#define PB_CAP 12288       // k_place LDS stage capacity (ints)

// workspace offsets (bytes), all 16B-aligned
#define O_CNT    0u          // N ints   (degree counts, later slow-path cursors)
#define O_DINV   524288u     // N floats (rsqrt(deg+1))
#define O_ROWPTR 1048576u    // N+1 ints
#define O_COL    1572864u    // E ints   (CSR src indices)
#define O_H1     14680064u   // N*16 floats ; ALSO gbuf (E uints, 12.8MB) during CSR build
#define O_OUT1   22020096u   // N*16 floats
#define O_H2     28835840u   // N*32 floats
#define O_BSUM   41943040u   // scan block sums (196 ints)
#define O_GCUR   41947136u   // NBUCK ints (bucket fill cursors)

// ---------------- CSR build ----------------

__global__ void k_count(const int* __restrict__ ei, int* __restrict__ cnt) {
    int e = blockIdx.x * blockDim.x + threadIdx.x;
    if (e < NEDGE) atomicAdd(&cnt[ei[NEDGE + e]], 1);
}

__global__ void k_dinv(const int* __restrict__ cnt, float* __restrict__ dinv) {
    int i = blockIdx.x * blockDim.x + threadIdx.x;
    if (i < N_NODES) dinv[i] = rsqrtf((float)cnt[i] + 1.0f);
}

__global__ void k_scan1(const int* __restrict__ cnt, int* __restrict__ rp, int* __restrict__ bsum) {
    __shared__ int s[512];
    int tid = threadIdx.x;
    int i = blockIdx.x * 512 + tid;
    int v = (i < N_NODES) ? cnt[i] : 0;
    s[tid] = v;
    __syncthreads();
    for (int off = 1; off < 512; off <<= 1) {
        int t = (tid >= off) ? s[tid - off] : 0;
        __syncthreads();
        s[tid] += t;
        __syncthreads();
    }
    if (i < N_NODES) rp[i] = s[tid] - v;   // exclusive within block
    if (tid == 511) bsum[blockIdx.x] = s[511];
}

#define NB_SCAN 196
__global__ void k_scan2(int* __restrict__ bsum) {
    __shared__ int s[256];
    int tid = threadIdx.x;
    int v = (tid < NB_SCAN) ? bsum[tid] : 0;
    s[tid] = v;
    __syncthreads();
    for (int off = 1; off < 256; off <<= 1) {
        int t = (tid >= off) ? s[tid - off] : 0;
        __syncthreads();
        s[tid] += t;
        __syncthreads();
    }
    if (tid < NB_SCAN) bsum[tid] = s[tid] - v;  // exclusive block offsets
}

__global__ void k_scan3(int* __restrict__ rp, const int* __restrict__ bsum, int* __restrict__ cursor) {
    int i = blockIdx.x * 512 + threadIdx.x;
    if (i < N_NODES) {
        int v = rp[i] + bsum[blockIdx.x];
        rp[i] = v;
        cursor[i] = v;   // slow-path fill cursor starts at row begin
    }
    if (i == 0) rp[N_NODES] = NEDGE;
}

__global__ void k_ginit(const int* __restrict__ rp, int* __restrict__ gcur) {
    int i = threadIdx.x;
    if (i < NBUCK) gcur[i] = rp[i * 512];
}

// Phase A: multisplit edges into 196 dst-range buckets; all global stores
// are lane-contiguous (flush from LDS) to avoid partial-line write blowup.
__global__ __launch_bounds__(256) void k_bin(const int* __restrict__ ei,
                                             int* __restrict__ gcur,
                                             unsigned int* __restrict__ gbuf) {
    __shared__ int lcnt[256];
    __shared__ int lscan[256];
    __shared__ int lbase[256];
    __shared__ unsigned int sdat[BIN_C];
    __shared__ unsigned char sb[BIN_C];
    int tid = threadIdx.x;
    int e0 = blockIdx.x * BIN_C;

    lcnt[tid] = 0;
    __syncthreads();
    // pass 1: per-bucket counts
    #pragma unroll 4
    for (int j = 0; j < BIN_C / 256; ++j) {
        int e = e0 + j * 256 + tid;
        if (e < NEDGE) {
            int d = ei[NEDGE + e];
            atomicAdd(&lcnt[d >> 9], 1);
        }
    }
    __syncthreads();
    // inclusive Hillis-Steele scan over 256
    lscan[tid] = lcnt[tid];
    __syncthreads();
    for (int off = 1; off < 256; off <<= 1) {
        int t = (tid >= off) ? lscan[tid - off] : 0;
        __syncthreads();
        lscan[tid] += t;
        __syncthreads();
    }
    lscan[tid] -= lcnt[tid];   // exclusive
    if (tid < NBUCK) lbase[tid] = atomicAdd(&gcur[tid], lcnt[tid]);
    __syncthreads();
    lcnt[tid] = 0;
    __syncthreads();
    // pass 2: LDS scatter (second read of ei hits L2)
    #pragma unroll 4
    for (int j = 0; j < BIN_C / 256; ++j) {
        int e = e0 + j * 256 + tid;
        if (e < NEDGE) {
            int s = ei[e];
            int d = ei[NEDGE + e];
            int b = d >> 9;
            int p = lscan[b] + atomicAdd(&lcnt[b], 1);
            sdat[p] = (unsigned int)s | ((unsigned int)(d & 511) << 17);
            sb[p] = (unsigned char)b;
        }
    }
    __syncthreads();
    // flush: lane-contiguous global stores
    int tot = (e0 + BIN_C <= NEDGE) ? BIN_C : (NEDGE - e0);
    for (int i = tid; i < tot; i += 256) {
        int b = sb[i];
        gbuf[lbase[b] + (i - lscan[b])] = sdat[i];
    }
}

// Phase B: one block per 256-node half-bucket; build its col window in LDS,
// dump with full-line coalesced stores.
__global__ __launch_bounds__(256) void k_place(const int* __restrict__ rp,
                                               const unsigned int* __restrict__ gbuf,
                                               int* __restrict__ col,
                                               int* __restrict__ cnt) {
    __shared__ int scat[PB_CAP];
    __shared__ int lcur[257];
    int h = blockIdx.x;
    int b = h >> 1;
    int half = h & 1;
    int n0h = b * 512 + half * 256;
    if (n0h >= N_NODES) return;
    int nn = min(256, N_NODES - n0h);
    int tid = threadIdx.x;
    int bbeg = rp[b * 512];
    int bend = rp[min(b * 512 + 512, N_NODES)];
    int hbeg = rp[n0h];
    int hend = rp[n0h + nn];
    int nregh = hend - hbeg;

    if (tid < nn) lcur[tid] = rp[n0h + tid] - hbeg;
    __syncthreads();

    if (nregh <= PB_CAP) {
        for (int i = bbeg + tid; i < bend; i += 256) {
            unsigned int v = gbuf[i];
            int dl = (int)(v >> 17);
            if ((dl >> 8) == half) {
                int dlh = dl & 255;
                if (dlh < nn) {
                    int p = atomicAdd(&lcur[dlh], 1);
                    scat[p] = (int)(v & 0x1FFFFu);
                }
            }
        }
        __syncthreads();
        for (int i = tid; i < nregh; i += 256)
            col[hbeg + i] = scat[i];
    } else {
        // statistically-unreachable fallback: direct scatter via global cursors
        for (int i = bbeg + tid; i < bend; i += 256) {
            unsigned int v = gbuf[i];
            int dl = (int)(v >> 17);
            if ((dl >> 8) == half) {
                int d = b * 512 + dl;
                int p = atomicAdd(&cnt[d], 1);
                col[p] = (int)(v & 0x1FFFFu);
            }
        }
    }
}

// ---------------- GEMM1: h1 = x @ W1  [100000x512]x[512x16] ----------------

#define G1_ROWS 256
#define G1_KC 32
#define XS_PAD 260   // 256 rows + pad, keeps ds_read_b128 ~2-way

__global__ __launch_bounds__(256) void k_gemm1(const float* __restrict__ x,
                                               const float* __restrict__ W1,
                                               float* __restrict__ h1) {
    __shared__ float xs[G1_KC][XS_PAD];  // transposed: [k][row]
    __shared__ float ws[G1_KC][16];      // [k][c]
    int tid = threadIdx.x;
    int r0 = blockIdx.x * G1_ROWS;
    int rg = tid >> 2;   // 0..63 : 4 rows each
    int cg = tid & 3;    // 0..3  : 4 cols each
    float acc[4][4] = {{0.f}};

    for (int k0 = 0; k0 < FEAT_IN; k0 += G1_KC) {
        __syncthreads();
        #pragma unroll
        for (int jj = 0; jj < 8; ++jj) {
            int linear = tid + jj * 256;      // float4 index 0..2047
            int row = linear >> 3;            // 8 float4 per row
            int kq  = linear & 7;
            float4 xv = make_float4(0.f, 0.f, 0.f, 0.f);
            if (r0 + row < N_NODES)
                xv = *reinterpret_cast<const float4*>(&x[(size_t)(r0 + row) * FEAT_IN + k0 + kq * 4]);
            xs[kq * 4 + 0][row] = xv.x;
            xs[kq * 4 + 1][row] = xv.y;
            xs[kq * 4 + 2][row] = xv.z;
            xs[kq * 4 + 3][row] = xv.w;
        }
        if (tid < 128) {
            float4 wv = *reinterpret_cast<const float4*>(&W1[k0 * 16 + tid * 4]);
            *reinterpret_cast<float4*>(&ws[0][0] + tid * 4) = wv;
        }
        __syncthreads();
        #pragma unroll
        for (int k = 0; k < G1_KC; ++k) {
            float4 xv = *reinterpret_cast<const float4*>(&xs[k][rg * 4]);
            float4 wv = *reinterpret_cast<const float4*>(&ws[k][cg * 4]);
            float xa[4] = {xv.x, xv.y, xv.z, xv.w};
            float wa[4] = {wv.x, wv.y, wv.z, wv.w};
            #pragma unroll
            for (int i = 0; i < 4; ++i)
                #pragma unroll
                for (int j = 0; j < 4; ++j)
                    acc[i][j] += xa[i] * wa[j];
        }
    }
    #pragma unroll
    for (int i = 0; i < 4; ++i) {
        int row = r0 + rg * 4 + i;
        if (row < N_NODES) {
            float4 o = make_float4(acc[i][0], acc[i][1], acc[i][2], acc[i][3]);
            *reinterpret_cast<float4*>(&h1[row * C1 + cg * 4]) = o;
        }
    }
}

// ---------------- gather layer 1 (fused norm+selfloop+bias+relu) ----------------

__global__ __launch_bounds__(256) void k_gather1(const int* __restrict__ rp, const int* __restrict__ col,
                                                 const float* __restrict__ dinv, const float* __restrict__ h1,
                                                 const float* __restrict__ b1, float* __restrict__ out1) {
    int t = blockIdx.x * 256 + threadIdx.x;
    int node = t >> 4;
    int c = t & 15;
    int beg = rp[node], end = rp[node + 1];
    float di = dinv[node];
    float acc = 0.f;
    for (int p = beg; p < end; ++p) {
        int s = col[p];
        acc += dinv[s] * h1[s * C1 + c];
    }
    float v = di * acc + h1[node * C1 + c] * (di * di) + b1[c];
    out1[node * C1 + c] = fmaxf(v, 0.0f);
}

// ---------------- GEMM2: h2 = out1 @ W2  [100000x16]x[16x32] ----------------

__global__ __launch_bounds__(256) void k_gemm2(const float* __restrict__ in,
                                               const float* __restrict__ W2,
                                               float* __restrict__ h2) {
    __shared__ float ws[16 * 32];
    int tid = threadIdx.x;
    if (tid < 128) {
        float4 wv = *reinterpret_cast<const float4*>(&W2[tid * 4]);
        *reinterpret_cast<float4*>(&ws[tid * 4]) = wv;
    }
    __syncthreads();
    int t = blockIdx.x * 256 + tid;
    int node = t >> 5;
    int c = t & 31;
    const float4* rowp = reinterpret_cast<const float4*>(&in[node * C1]);
    float4 a = rowp[0], b = rowp[1], cc = rowp[2], d = rowp[3];
    float rv[16] = {a.x, a.y, a.z, a.w, b.x, b.y, b.z, b.w,
                    cc.x, cc.y, cc.z, cc.w, d.x, d.y, d.z, d.w};
    float acc = 0.f;
    #pragma unroll
    for (int k = 0; k < 16; ++k) acc += rv[k] * ws[k * 32 + c];
    h2[node * C2 + c] = acc;
}

// ---------------- gather layer 2 -> d_out (ppi) ----------------

__global__ __launch_bounds__(256) void k_gather2(const int* __restrict__ rp, const int* __restrict__ col,
                                                 const float* __restrict__ dinv, const float* __restrict__ h2,
                                                 const float* __restrict__ b2, float* __restrict__ out) {
    int t = blockIdx.x * 256 + threadIdx.x;
    int node = t >> 5;
    int c = t & 31;
    int beg = rp[node], end = rp[node + 1];
    float di = dinv[node];
    float acc = 0.f;
    for (int p = beg; p < end; ++p) {
        int s = col[p];
        acc += dinv[s] * h2[s * C2 + c];
    }
    float v = di * acc + h2[node * C2 + c] * (di * di) + b2[c];
    out[node * C2 + c] = fmaxf(v, 0.0f);
}

// ---------------- DDI branch: fc1+relu -> fc2+relu -> fc3+relu ----------------

#define DDI_CHUNK 132   // 1056 = 8 * 132

__global__ __launch_bounds__(256) void k_ddi(const float* __restrict__ feat,
                                             const float* __restrict__ fW1, const float* __restrict__ fb1,
                                             const float* __restrict__ fW2, const float* __restrict__ fb2,
                                             const float* __restrict__ fW3, const float* __restrict__ fb3,
                                             float* __restrict__ out) {
    __shared__ float sW[DDI_CHUNK * 64];
    __shared__ float sH[4][64];
    int tid = threadIdx.x;
    int wave = tid >> 6;
    int lane = tid & 63;
    int row = blockIdx.x * 4 + wave;

    float acc = 0.f;
    for (int k0 = 0; k0 < F_DDI; k0 += DDI_CHUNK) {
        __syncthreads();
        for (int idx = tid; idx < DDI_CHUNK * 64; idx += 256)
            sW[idx] = fW1[k0 * 64 + idx];
        __syncthreads();
        const float* frow = &feat[(size_t)row * F_DDI + k0];
        #pragma unroll 4
        for (int kk = 0; kk < DDI_CHUNK; kk += 4) {
            float4 fv = *reinterpret_cast<const float4*>(&frow[kk]);
            acc += fv.x * sW[(kk + 0) * 64 + lane];
            acc += fv.y * sW[(kk + 1) * 64 + lane];
            acc += fv.z * sW[(kk + 2) * 64 + lane];
            acc += fv.w * sW[(kk + 3) * 64 + lane];
        }
    }
    float h = fmaxf(acc + fb1[lane], 0.f);
    __syncthreads();
    sH[wave][lane] = h;
    __syncthreads();

    int c16 = lane & 15;
    float acc2 = 0.f;
    #pragma unroll
    for (int kk = 0; kk < 64; ++kk)
        acc2 += sH[wave][kk] * fW2[kk * 16 + c16];
    float o2 = fmaxf(acc2 + fb2[c16], 0.f);
    float part = o2 * fW3[c16];
    #pragma unroll
    for (int off = 8; off >= 1; off >>= 1)
        part += __shfl_xor(part, off, 16);
    if (lane == 0)
        out[row] = fmaxf(part + fb3[0], 0.f);
}

// ---------------- launch ----------------

extern "C" void kernel_launch(void* const* d_in, const int* in_sizes, int n_in,
                              void* d_out, int out_size, void* d_ws, size_t ws_size,
                              hipStream_t stream) {
    const float* x   = (const float*)d_in[0];
    const int*   ei  = (const int*)d_in[1];
    const float* ddi = (const float*)d_in[2];
    const float* W1  = (const float*)d_in[3];
    const float* b1  = (const float*)d_in[4];
    const float* W2  = (const float*)d_in[5];
    const float* b2  = (const float*)d_in[6];
    const float* fW1 = (const float*)d_in[7];
    const float* fb1 = (const float*)d_in[8];
    const float* fW2 = (const float*)d_in[9];
    const float* fb2 = (const float*)d_in[10];
    const float* fW3 = (const float*)d_in[11];
    const float* fb3 = (const float*)d_in[12];

    char* ws = (char*)d_ws;
    int*   cnt   = (int*)(ws + O_CNT);
    float* dinv  = (float*)(ws + O_DINV);
    int*   rp    = (int*)(ws + O_ROWPTR);
    int*   col   = (int*)(ws + O_COL);
    float* h1    = (float*)(ws + O_H1);
    float* out1  = (float*)(ws + O_OUT1);
    float* h2    = (float*)(ws + O_H2);
    int*   bsum  = (int*)(ws + O_BSUM);
    int*   gcur  = (int*)(ws + O_GCUR);
    unsigned int* gbuf = (unsigned int*)(ws + O_H1);  // aliases h1/out1 during CSR build

    float* out_ppi = (float*)d_out;
    float* out_ddi = out_ppi + (size_t)N_NODES * C2;

    hipMemsetAsync(cnt, 0, N_NODES * sizeof(int), stream);
    k_count<<<NEDGE / 256, 256, 0, stream>>>(ei, cnt);
    k_dinv<<<(N_NODES + 255) / 256, 256, 0, stream>>>(cnt, dinv);
    k_scan1<<<NB_SCAN, 512, 0, stream>>>(cnt, rp, bsum);
    k_scan2<<<1, 256, 0, stream>>>(bsum);
    k_scan3<<<NB_SCAN, 512, 0, stream>>>(rp, bsum, cnt);
    k_ginit<<<1, 256, 0, stream>>>(rp, gcur);
    k_bin<<<NB_BIN, 256, 0, stream>>>(ei, gcur, gbuf);
    k_place<<<NBUCK * 2, 256, 0, stream>>>(rp, gbuf, col, cnt);

    k_gemm1<<<(N_NODES + G1_ROWS - 1) / G1_ROWS, 256, 0, stream>>>(x, W1, h1);
    k_gather1<<<N_NODES * C1 / 256, 256, 0, stream>>>(rp, col, dinv, h1, b1, out1);
    k_gemm2<<<N_NODES * C2 / 256, 256, 0, stream>>>(out1, W2, h2);
    k_gather2<<<N_NODES * C2 / 256, 256, 0, stream>>>(rp, col, dinv, h2, b2, out_ppi);

    k_ddi<<<B_DDI / 4, 256, 0, stream>>>(ddi, fW1, fb1, fW2, fb2, fW3, fb3, out_ddi);
}

// Round 3
// 396.732 us; speedup vs baseline: 2.0791x; 1.6297x over previous
//
#include <hip/hip_runtime.h>

#define N_NODES 100000
#define FEAT_IN 512
#define C1 16
#define C2 32
#define NEDGE 3200000
#define B_DDI 4096
#define F_DDI 1056

#define NBUCK 196          // 512-node dst buckets
#define BIN_C 12288        // edges per k_bin/k_bcnt block chunk
#define NB_BIN ((NEDGE + BIN_C - 1) / BIN_C)   // 261
#define PB_CAP 12288       // k_place scat capacity per half (ints)

// workspace offsets (bytes), all 16B-aligned
#define O_DINV   524288u     // N floats (rsqrt(deg+1))
#define O_ROWPTR 1048576u    // N+1 ints
#define O_COL    1572864u    // E ints   (CSR src indices)
#define O_H1     14680064u   // N*16 floats ; ALSO gbuf (E uints, 12.8MB) during CSR build
#define O_OUT1   22020096u   // N*16 floats
#define O_BCNT   41943040u   // NBUCK ints
#define O_BBASE  41944064u   // NBUCK+1 ints
#define O_GCUR   41945088u   // NBUCK ints

// ---------------- CSR build ----------------

// per-bucket histogram (LDS-privatized, one global atomic per bin per block)
__global__ __launch_bounds__(256) void k_bcnt(const int* __restrict__ ei, int* __restrict__ bcnt) {
    __shared__ int h[256];
    int tid = threadIdx.x;
    h[tid] = 0;
    __syncthreads();
    int e0 = blockIdx.x * BIN_C;
    #pragma unroll 4
    for (int j = 0; j < BIN_C / 256; ++j) {
        int e = e0 + j * 256 + tid;
        if (e < NEDGE) atomicAdd(&h[ei[NEDGE + e] >> 9], 1);
    }
    __syncthreads();
    if (tid < NBUCK && h[tid]) atomicAdd(&bcnt[tid], h[tid]);
}

__global__ void k_bscan(const int* __restrict__ bcnt, int* __restrict__ bbase,
                        int* __restrict__ gcur, int* __restrict__ rp) {
    __shared__ int s[256];
    int tid = threadIdx.x;
    int v = (tid < NBUCK) ? bcnt[tid] : 0;
    s[tid] = v;
    __syncthreads();
    for (int off = 1; off < 256; off <<= 1) {
        int t = (tid >= off) ? s[tid - off] : 0;
        __syncthreads();
        s[tid] += t;
        __syncthreads();
    }
    if (tid < NBUCK) { bbase[tid] = s[tid] - v; gcur[tid] = s[tid] - v; }
    if (tid == 0) { bbase[NBUCK] = NEDGE; rp[N_NODES] = NEDGE; }
}

// Phase A: multisplit edges into 196 dst-range buckets; all global stores
// are lane-contiguous (flush from LDS).
__global__ __launch_bounds__(256) void k_bin(const int* __restrict__ ei,
                                             int* __restrict__ gcur,
                                             unsigned int* __restrict__ gbuf) {
    __shared__ int lcnt[256];
    __shared__ int lscan[256];
    __shared__ int lbase[256];
    __shared__ unsigned int sdat[BIN_C];
    __shared__ unsigned char sb[BIN_C];
    int tid = threadIdx.x;
    int e0 = blockIdx.x * BIN_C;

    lcnt[tid] = 0;
    __syncthreads();
    #pragma unroll 4
    for (int j = 0; j < BIN_C / 256; ++j) {
        int e = e0 + j * 256 + tid;
        if (e < NEDGE) {
            int d = ei[NEDGE + e];
            atomicAdd(&lcnt[d >> 9], 1);
        }
    }
    __syncthreads();
    lscan[tid] = lcnt[tid];
    __syncthreads();
    for (int off = 1; off < 256; off <<= 1) {
        int t = (tid >= off) ? lscan[tid - off] : 0;
        __syncthreads();
        lscan[tid] += t;
        __syncthreads();
    }
    lscan[tid] -= lcnt[tid];   // exclusive
    if (tid < NBUCK) lbase[tid] = atomicAdd(&gcur[tid], lcnt[tid]);
    __syncthreads();
    lcnt[tid] = 0;
    __syncthreads();
    #pragma unroll 4
    for (int j = 0; j < BIN_C / 256; ++j) {
        int e = e0 + j * 256 + tid;
        if (e < NEDGE) {
            int s = ei[e];
            int d = ei[NEDGE + e];
            int b = d >> 9;
            int p = lscan[b] + atomicAdd(&lcnt[b], 1);
            sdat[p] = (unsigned int)s | ((unsigned int)(d & 511) << 17);
            sb[p] = (unsigned char)b;
        }
    }
    __syncthreads();
    int tot = (e0 + BIN_C <= NEDGE) ? BIN_C : (NEDGE - e0);
    for (int i = tid; i < tot; i += 256) {
        int b = sb[i];
        gbuf[lbase[b] + (i - lscan[b])] = sdat[i];
    }
}

// Phase B: one block per bucket (512 nodes). Counts per-node in LDS, scans,
// writes rp + dinv, then places edges via LDS stage (two half-rounds) and
// flushes col with coalesced stores.
__global__ __launch_bounds__(512) void k_place(const int* __restrict__ bbase,
                                               const unsigned int* __restrict__ gbuf,
                                               int* __restrict__ col,
                                               int* __restrict__ rp,
                                               float* __restrict__ dinv) {
    __shared__ int scat[PB_CAP];
    __shared__ int cnt[512];
    __shared__ int loc[512];
    __shared__ int lcur[512];
    int b = blockIdx.x;
    int tid = threadIdx.x;
    int beg = bbase[b], end = bbase[b + 1];
    int n0 = b * 512;

    cnt[tid] = 0;
    __syncthreads();
    for (int i = beg + tid; i < end; i += 512)
        atomicAdd(&cnt[gbuf[i] >> 17], 1);
    __syncthreads();
    int v = cnt[tid];
    loc[tid] = v;
    __syncthreads();
    for (int off = 1; off < 512; off <<= 1) {
        int t = (tid >= off) ? loc[tid - off] : 0;
        __syncthreads();
        loc[tid] += t;
        __syncthreads();
    }
    int ex = loc[tid] - v;     // exclusive prefix within bucket
    lcur[tid] = ex;
    int n = n0 + tid;
    if (n < N_NODES) {
        rp[n] = beg + ex;
        dinv[n] = rsqrtf((float)v + 1.0f);
    }
    __syncthreads();
    int h0 = loc[255];          // edges belonging to first 256 nodes
    int tot = end - beg;

    if (h0 <= PB_CAP && (tot - h0) <= PB_CAP) {
        // round A: local nodes 0..255
        for (int i = beg + tid; i < end; i += 512) {
            unsigned int u = gbuf[i];
            int d = (int)(u >> 17);
            if (d < 256) {
                int p = atomicAdd(&lcur[d], 1);
                scat[p] = (int)(u & 0x1FFFFu);
            }
        }
        __syncthreads();
        for (int i = tid; i < h0; i += 512)
            col[beg + i] = scat[i];
        __syncthreads();
        // round B: local nodes 256..511 (offsets shifted by h0 into scat)
        for (int i = beg + tid; i < end; i += 512) {
            unsigned int u = gbuf[i];
            int d = (int)(u >> 17);
            if (d >= 256) {
                int p = atomicAdd(&lcur[d], 1);
                scat[p - h0] = (int)(u & 0x1FFFFu);
            }
        }
        __syncthreads();
        for (int i = tid; i < tot - h0; i += 512)
            col[beg + h0 + i] = scat[i];
    } else {
        // statistically-unreachable fallback: direct scatter
        for (int i = beg + tid; i < end; i += 512) {
            unsigned int u = gbuf[i];
            int p = atomicAdd(&lcur[u >> 17], 1);
            col[beg + p] = (int)(u & 0x1FFFFu);
        }
    }
}

// ---------------- GEMM1: h1 = x @ W1  [100000x512]x[512x16] ----------------

#define G1_ROWS 256
#define G1_KC 32
#define XS_PAD 260

__global__ __launch_bounds__(256) void k_gemm1(const float* __restrict__ x,
                                               const float* __restrict__ W1,
                                               float* __restrict__ h1) {
    __shared__ float xs[G1_KC][XS_PAD];  // transposed: [k][row]
    __shared__ float ws[G1_KC][16];      // [k][c]
    int tid = threadIdx.x;
    int r0 = blockIdx.x * G1_ROWS;
    int rg = tid >> 2;
    int cg = tid & 3;
    float acc[4][4] = {{0.f}};

    for (int k0 = 0; k0 < FEAT_IN; k0 += G1_KC) {
        __syncthreads();
        #pragma unroll
        for (int jj = 0; jj < 8; ++jj) {
            int linear = tid + jj * 256;
            int row = linear >> 3;
            int kq  = linear & 7;
            float4 xv = make_float4(0.f, 0.f, 0.f, 0.f);
            if (r0 + row < N_NODES)
                xv = *reinterpret_cast<const float4*>(&x[(size_t)(r0 + row) * FEAT_IN + k0 + kq * 4]);
            xs[kq * 4 + 0][row] = xv.x;
            xs[kq * 4 + 1][row] = xv.y;
            xs[kq * 4 + 2][row] = xv.z;
            xs[kq * 4 + 3][row] = xv.w;
        }
        if (tid < 128) {
            float4 wv = *reinterpret_cast<const float4*>(&W1[k0 * 16 + tid * 4]);
            *reinterpret_cast<float4*>(&ws[0][0] + tid * 4) = wv;
        }
        __syncthreads();
        #pragma unroll
        for (int k = 0; k < G1_KC; ++k) {
            float4 xv = *reinterpret_cast<const float4*>(&xs[k][rg * 4]);
            float4 wv = *reinterpret_cast<const float4*>(&ws[k][cg * 4]);
            float xa[4] = {xv.x, xv.y, xv.z, xv.w};
            float wa[4] = {wv.x, wv.y, wv.z, wv.w};
            #pragma unroll
            for (int i = 0; i < 4; ++i)
                #pragma unroll
                for (int j = 0; j < 4; ++j)
                    acc[i][j] += xa[i] * wa[j];
        }
    }
    #pragma unroll
    for (int i = 0; i < 4; ++i) {
        int row = r0 + rg * 4 + i;
        if (row < N_NODES) {
            float4 o = make_float4(acc[i][0], acc[i][1], acc[i][2], acc[i][3]);
            *reinterpret_cast<float4*>(&h1[row * C1 + cg * 4]) = o;
        }
    }
}

// ---------------- gather layer 1 (fused norm+selfloop+bias+relu) ----------------

__global__ __launch_bounds__(256) void k_gather1(const int* __restrict__ rp, const int* __restrict__ col,
                                                 const float* __restrict__ dinv, const float* __restrict__ h1,
                                                 const float* __restrict__ b1, float* __restrict__ out1) {
    int t = blockIdx.x * 256 + threadIdx.x;
    int node = t >> 4;
    int c = t & 15;
    int beg = rp[node], end = rp[node + 1];
    float di = dinv[node];
    float acc = 0.f;
    int p = beg;
    for (; p + 1 < end; p += 2) {
        int s0 = col[p], s1 = col[p + 1];
        float a0 = dinv[s0] * h1[s0 * C1 + c];
        float a1 = dinv[s1] * h1[s1 * C1 + c];
        acc += a0 + a1;
    }
    if (p < end) {
        int s = col[p];
        acc += dinv[s] * h1[s * C1 + c];
    }
    float v = di * acc + h1[node * C1 + c] * (di * di) + b1[c];
    out1[node * C1 + c] = fmaxf(v, 0.0f);
}

// ---------------- gather layer 2 + fused W2/b2/relu -> d_out (ppi) ----------------
// out[dst] = relu( (di*sum(norm*out1[src]) + di^2*out1[dst]) @ W2 + b2 )

__global__ __launch_bounds__(256) void k_gather2(const int* __restrict__ rp, const int* __restrict__ col,
                                                 const float* __restrict__ dinv, const float* __restrict__ out1,
                                                 const float* __restrict__ W2, const float* __restrict__ b2,
                                                 float* __restrict__ out) {
    __shared__ float sacc[16][17];
    __shared__ float sW[16 * 32];
    __shared__ float sb[32];
    int tid = threadIdx.x;
    if (tid < 128)
        *reinterpret_cast<float4*>(&sW[tid * 4]) = *reinterpret_cast<const float4*>(&W2[tid * 4]);
    if (tid < 32) sb[tid] = b2[tid];
    int g = tid >> 4;
    int c = tid & 15;
    int node = blockIdx.x * 16 + g;
    int beg = rp[node], end = rp[node + 1];
    float di = dinv[node];
    float acc = 0.f;
    int p = beg;
    for (; p + 1 < end; p += 2) {
        int s0 = col[p], s1 = col[p + 1];
        float a0 = dinv[s0] * out1[s0 * C1 + c];
        float a1 = dinv[s1] * out1[s1 * C1 + c];
        acc += a0 + a1;
    }
    if (p < end) {
        int s = col[p];
        acc += dinv[s] * out1[s * C1 + c];
    }
    sacc[g][c] = di * acc + (di * di) * out1[node * C1 + c];
    __syncthreads();
    float r0 = sb[c], r1 = sb[c + 16];
    #pragma unroll
    for (int k = 0; k < 16; ++k) {
        float a = sacc[g][k];
        r0 += a * sW[k * 32 + c];
        r1 += a * sW[k * 32 + c + 16];
    }
    out[node * C2 + c] = fmaxf(r0, 0.f);
    out[node * C2 + c + 16] = fmaxf(r1, 0.f);
}

// ---------------- DDI branch ----------------

#define DDI_CHUNK 132   // 1056 = 8 * 132

__global__ __launch_bounds__(256) void k_ddi(const float* __restrict__ feat,
                                             const float* __restrict__ fW1, const float* __restrict__ fb1,
                                             const float* __restrict__ fW2, const float* __restrict__ fb2,
                                             const float* __restrict__ fW3, const float* __restrict__ fb3,
                                             float* __restrict__ out) {
    __shared__ float sW[DDI_CHUNK * 64];
    __shared__ float sH[4][64];
    int tid = threadIdx.x;
    int wave = tid >> 6;
    int lane = tid & 63;
    int row = blockIdx.x * 4 + wave;

    float acc = 0.f;
    for (int k0 = 0; k0 < F_DDI; k0 += DDI_CHUNK) {
        __syncthreads();
        for (int idx = tid; idx < DDI_CHUNK * 64; idx += 256)
            sW[idx] = fW1[k0 * 64 + idx];
        __syncthreads();
        const float* frow = &feat[(size_t)row * F_DDI + k0];
        #pragma unroll 4
        for (int kk = 0; kk < DDI_CHUNK; kk += 4) {
            float4 fv = *reinterpret_cast<const float4*>(&frow[kk]);
            acc += fv.x * sW[(kk + 0) * 64 + lane];
            acc += fv.y * sW[(kk + 1) * 64 + lane];
            acc += fv.z * sW[(kk + 2) * 64 + lane];
            acc += fv.w * sW[(kk + 3) * 64 + lane];
        }
    }
    float h = fmaxf(acc + fb1[lane], 0.f);
    __syncthreads();
    sH[wave][lane] = h;
    __syncthreads();

    int c16 = lane & 15;
    float acc2 = 0.f;
    #pragma unroll
    for (int kk = 0; kk < 64; ++kk)
        acc2 += sH[wave][kk] * fW2[kk * 16 + c16];
    float o2 = fmaxf(acc2 + fb2[c16], 0.f);
    float part = o2 * fW3[c16];
    #pragma unroll
    for (int off = 8; off >= 1; off >>= 1)
        part += __shfl_xor(part, off, 16);
    if (lane == 0)
        out[row] = fmaxf(part + fb3[0], 0.f);
}

// ---------------- launch ----------------

extern "C" void kernel_launch(void* const* d_in, const int* in_sizes, int n_in,
                              void* d_out, int out_size, void* d_ws, size_t ws_size,
                              hipStream_t stream) {
    const float* x   = (const float*)d_in[0];
    const int*   ei  = (const int*)d_in[1];
    const float* ddi = (const float*)d_in[2];
    const float* W1  = (const float*)d_in[3];
    const float* b1  = (const float*)d_in[4];
    const float* W2  = (const float*)d_in[5];
    const float* b2  = (const float*)d_in[6];
    const float* fW1 = (const float*)d_in[7];
    const float* fb1 = (const float*)d_in[8];
    const float* fW2 = (const float*)d_in[9];
    const float* fb2 = (const float*)d_in[10];
    const float* fW3 = (const float*)d_in[11];
    const float* fb3 = (const float*)d_in[12];

    char* ws = (char*)d_ws;
    float* dinv  = (float*)(ws + O_DINV);
    int*   rp    = (int*)(ws + O_ROWPTR);
    int*   col   = (int*)(ws + O_COL);
    float* h1    = (float*)(ws + O_H1);
    float* out1  = (float*)(ws + O_OUT1);
    int*   bcnt  = (int*)(ws + O_BCNT);
    int*   bbase = (int*)(ws + O_BBASE);
    int*   gcur  = (int*)(ws + O_GCUR);
    unsigned int* gbuf = (unsigned int*)(ws + O_H1);  // aliases h1/out1 during CSR build

    float* out_ppi = (float*)d_out;
    float* out_ddi = out_ppi + (size_t)N_NODES * C2;

    hipMemsetAsync(bcnt, 0, NBUCK * sizeof(int), stream);
    k_bcnt<<<NB_BIN, 256, 0, stream>>>(ei, bcnt);
    k_bscan<<<1, 256, 0, stream>>>(bcnt, bbase, gcur, rp);
    k_bin<<<NB_BIN, 256, 0, stream>>>(ei, gcur, gbuf);
    k_place<<<NBUCK, 512, 0, stream>>>(bbase, gbuf, col, rp, dinv);

    k_gemm1<<<(N_NODES + G1_ROWS - 1) / G1_ROWS, 256, 0, stream>>>(x, W1, h1);
    k_gather1<<<N_NODES * C1 / 256, 256, 0, stream>>>(rp, col, dinv, h1, b1, out1);
    k_gather2<<<N_NODES / 16, 256, 0, stream>>>(rp, col, dinv, out1, W2, b2, out_ppi);

    k_ddi<<<B_DDI / 4, 256, 0, stream>>>(ddi, fW1, fb1, fW2, fb2, fW3, fb3, out_ddi);
}

// Round 4
// 358.482 us; speedup vs baseline: 2.3010x; 1.1067x over previous
//
#include <hip/hip_runtime.h>

#define N_NODES 100000
#define HALF_N  50000
#define FEAT_IN 512
#define C1 16
#define C2 32
#define NEDGE 3200000
#define B_DDI 4096
#define F_DDI 1056

#define NBUCK 196          // 512-node dst buckets
#define BIN_C 12288        // edges per k_bin/k_bcnt block chunk
#define NB_BIN ((NEDGE + BIN_C - 1) / BIN_C)   // 261
#define PB_CAP 12288       // k_place scat capacity per half (ints)

// workspace offsets (bytes), all 16B-aligned
#define O_DINV   0u          // N floats
#define O_RP2    524288u     // 2N+1 ints (per-(node,half) row ptrs)
#define O_COL    1572864u    // E ints (CSR src indices, half-partitioned per row)
#define O_H1     14680064u   // N*16 floats ; gbuf (E uints) aliases during CSR build
#define O_OUT1   27525120u   // N*16 floats
#define O_TACC   34603008u   // N*16 floats (pass-A partial acc)
#define O_BCNT   41943040u   // NBUCK ints
#define O_BBASE  41944064u   // NBUCK+1 ints
#define O_GCUR   41945088u   // NBUCK ints

// ---------------- CSR build ----------------

__global__ __launch_bounds__(256) void k_bcnt(const int* __restrict__ ei, int* __restrict__ bcnt) {
    __shared__ int h[256];
    int tid = threadIdx.x;
    h[tid] = 0;
    __syncthreads();
    int e0 = blockIdx.x * BIN_C;
    #pragma unroll 4
    for (int j = 0; j < BIN_C / 256; ++j) {
        int e = e0 + j * 256 + tid;
        if (e < NEDGE) atomicAdd(&h[ei[NEDGE + e] >> 9], 1);
    }
    __syncthreads();
    if (tid < NBUCK && h[tid]) atomicAdd(&bcnt[tid], h[tid]);
}

__global__ void k_bscan(const int* __restrict__ bcnt, int* __restrict__ bbase,
                        int* __restrict__ gcur, int* __restrict__ rp2) {
    __shared__ int s[256];
    int tid = threadIdx.x;
    int v = (tid < NBUCK) ? bcnt[tid] : 0;
    s[tid] = v;
    __syncthreads();
    for (int off = 1; off < 256; off <<= 1) {
        int t = (tid >= off) ? s[tid - off] : 0;
        __syncthreads();
        s[tid] += t;
        __syncthreads();
    }
    if (tid < NBUCK) { bbase[tid] = s[tid] - v; gcur[tid] = s[tid] - v; }
    if (tid == 0) { bbase[NBUCK] = NEDGE; rp2[2 * N_NODES] = NEDGE; }
}

// Phase A: multisplit into 196 dst-buckets; stores lane-contiguous via LDS.
__global__ __launch_bounds__(256) void k_bin(const int* __restrict__ ei,
                                             int* __restrict__ gcur,
                                             unsigned int* __restrict__ gbuf) {
    __shared__ int lcnt[256];
    __shared__ int lscan[256];
    __shared__ int lbase[256];
    __shared__ unsigned int sdat[BIN_C];
    __shared__ unsigned char sb[BIN_C];
    int tid = threadIdx.x;
    int e0 = blockIdx.x * BIN_C;

    lcnt[tid] = 0;
    __syncthreads();
    #pragma unroll 4
    for (int j = 0; j < BIN_C / 256; ++j) {
        int e = e0 + j * 256 + tid;
        if (e < NEDGE) atomicAdd(&lcnt[ei[NEDGE + e] >> 9], 1);
    }
    __syncthreads();
    lscan[tid] = lcnt[tid];
    __syncthreads();
    for (int off = 1; off < 256; off <<= 1) {
        int t = (tid >= off) ? lscan[tid - off] : 0;
        __syncthreads();
        lscan[tid] += t;
        __syncthreads();
    }
    lscan[tid] -= lcnt[tid];   // exclusive
    if (tid < NBUCK) lbase[tid] = atomicAdd(&gcur[tid], lcnt[tid]);
    __syncthreads();
    lcnt[tid] = 0;
    __syncthreads();
    #pragma unroll 4
    for (int j = 0; j < BIN_C / 256; ++j) {
        int e = e0 + j * 256 + tid;
        if (e < NEDGE) {
            int s = ei[e];
            int d = ei[NEDGE + e];
            int b = d >> 9;
            int p = lscan[b] + atomicAdd(&lcnt[b], 1);
            sdat[p] = (unsigned int)s | ((unsigned int)(d & 511) << 17);
            sb[p] = (unsigned char)b;
        }
    }
    __syncthreads();
    int tot = (e0 + BIN_C <= NEDGE) ? BIN_C : (NEDGE - e0);
    for (int i = tid; i < tot; i += 256) {
        int b = sb[i];
        gbuf[lbase[b] + (i - lscan[b])] = sdat[i];
    }
}

// Phase B: per bucket, count per (node, src-half) -> scan -> rp2/dinv, then
// place edges (half-partitioned within each row) via LDS stage, coalesced flush.
__global__ __launch_bounds__(512) void k_place(const int* __restrict__ bbase,
                                               const unsigned int* __restrict__ gbuf,
                                               int* __restrict__ col,
                                               int* __restrict__ rp2,
                                               float* __restrict__ dinv) {
    __shared__ int scat[PB_CAP];
    __shared__ int cnt2[1024];
    __shared__ int sc[512];
    __shared__ int lcur[1024];
    int b = blockIdx.x;
    int tid = threadIdx.x;
    int beg = bbase[b], end = bbase[b + 1];
    int n0 = b * 512;

    cnt2[tid] = 0; cnt2[tid + 512] = 0;
    __syncthreads();
    for (int i = beg + tid; i < end; i += 512) {
        unsigned int u = gbuf[i];
        int dl = (int)(u >> 17);
        int src = (int)(u & 0x1FFFFu);
        atomicAdd(&cnt2[dl * 2 + (src >= HALF_N)], 1);
    }
    __syncthreads();
    int a = cnt2[2 * tid], bb = cnt2[2 * tid + 1];
    sc[tid] = a + bb;
    __syncthreads();
    for (int off = 1; off < 512; off <<= 1) {
        int t = (tid >= off) ? sc[tid - off] : 0;
        __syncthreads();
        sc[tid] += t;
        __syncthreads();
    }
    int ex = sc[tid] - (a + bb);
    lcur[2 * tid] = ex;
    lcur[2 * tid + 1] = ex + a;
    int n = n0 + tid;
    if (n < N_NODES) {
        rp2[2 * n] = beg + ex;
        rp2[2 * n + 1] = beg + ex + a;
        dinv[n] = rsqrtf((float)(a + bb) + 1.0f);
    }
    __syncthreads();
    int h0 = sc[255];
    int tot = end - beg;

    if (h0 <= PB_CAP && (tot - h0) <= PB_CAP) {
        for (int i = beg + tid; i < end; i += 512) {
            unsigned int u = gbuf[i];
            int dl = (int)(u >> 17);
            int src = (int)(u & 0x1FFFFu);
            if (dl < 256) {
                int p = atomicAdd(&lcur[dl * 2 + (src >= HALF_N)], 1);
                scat[p] = src;
            }
        }
        __syncthreads();
        for (int i = tid; i < h0; i += 512) col[beg + i] = scat[i];
        __syncthreads();
        for (int i = beg + tid; i < end; i += 512) {
            unsigned int u = gbuf[i];
            int dl = (int)(u >> 17);
            int src = (int)(u & 0x1FFFFu);
            if (dl >= 256) {
                int p = atomicAdd(&lcur[dl * 2 + (src >= HALF_N)], 1);
                scat[p - h0] = src;
            }
        }
        __syncthreads();
        for (int i = tid; i < tot - h0; i += 512) col[beg + h0 + i] = scat[i];
    } else {
        // statistically-unreachable fallback: direct scatter (keeps half order)
        for (int i = beg + tid; i < end; i += 512) {
            unsigned int u = gbuf[i];
            int dl = (int)(u >> 17);
            int src = (int)(u & 0x1FFFFu);
            int p = atomicAdd(&lcur[dl * 2 + (src >= HALF_N)], 1);
            col[beg + p] = src;
        }
    }
}

// ---------------- GEMM1: h1 = x @ W1, barrier-free streaming ----------------
// Block = 64 rows x 4 waves; wave w computes k-slice [w*128, w*128+128).
// W1 accessed at wave-uniform k -> scalar-cache loads. x: one 64B line per
// thread per 16-k step, fully consumed. Partials combined once via LDS.

__global__ __launch_bounds__(256) void k_gemm1(const float* __restrict__ x,
                                               const float* __restrict__ W1,
                                               float* __restrict__ h1) {
    __shared__ float part[4][64][17];
    int tid = threadIdx.x;
    int wv = __builtin_amdgcn_readfirstlane(tid >> 6);   // wave-uniform
    int lane = tid & 63;
    int row = blockIdx.x * 64 + lane;
    int crow = row < N_NODES ? row : N_NODES - 1;
    const float* __restrict__ xr = x + (size_t)crow * FEAT_IN + wv * 128;

    float acc[16];
    #pragma unroll
    for (int c = 0; c < 16; ++c) acc[c] = 0.f;

    for (int it = 0; it < 8; ++it) {
        const float4* xp = reinterpret_cast<const float4*>(xr + it * 16);
        float4 xv0 = xp[0], xv1 = xp[1], xv2 = xp[2], xv3 = xp[3];
        float xs[16] = {xv0.x, xv0.y, xv0.z, xv0.w, xv1.x, xv1.y, xv1.z, xv1.w,
                        xv2.x, xv2.y, xv2.z, xv2.w, xv3.x, xv3.y, xv3.z, xv3.w};
        int kb = wv * 128 + it * 16;
        #pragma unroll
        for (int j = 0; j < 16; ++j) {
            const float* __restrict__ wr = W1 + (size_t)(kb + j) * 16;  // uniform addr
            #pragma unroll
            for (int c = 0; c < 16; ++c) acc[c] = fmaf(xs[j], wr[c], acc[c]);
        }
    }
    #pragma unroll
    for (int c = 0; c < 16; ++c) part[wv][lane][c] = acc[c];
    __syncthreads();

    int r2 = tid >> 2, cq = tid & 3;
    int grow = blockIdx.x * 64 + r2;
    if (grow < N_NODES) {
        float o[4];
        #pragma unroll
        for (int j = 0; j < 4; ++j) {
            int c = cq * 4 + j;
            o[j] = part[0][r2][c] + part[1][r2][c] + part[2][r2][c] + part[3][r2][c];
        }
        *reinterpret_cast<float4*>(&h1[(size_t)grow * C1 + cq * 4]) =
            make_float4(o[0], o[1], o[2], o[3]);
    }
}

// ---------------- gathers: pass A (src<HALF_N slice), pass B (rest + finish) ----

__global__ __launch_bounds__(256) void k_gatherA(const int* __restrict__ rp2, const int* __restrict__ col,
                                                 const float* __restrict__ dinv, const float* __restrict__ tbl,
                                                 float* __restrict__ tacc) {
    int t = blockIdx.x * 256 + threadIdx.x;
    int node = t >> 4;
    int c = t & 15;
    int beg = rp2[2 * node], end = rp2[2 * node + 1];
    float acc = 0.f;
    int p = beg;
    for (; p + 1 < end; p += 2) {
        int s0 = col[p], s1 = col[p + 1];
        acc += dinv[s0] * tbl[s0 * C1 + c] + dinv[s1] * tbl[s1 * C1 + c];
    }
    if (p < end) {
        int s = col[p];
        acc += dinv[s] * tbl[s * C1 + c];
    }
    tacc[node * C1 + c] = acc;
}

__global__ __launch_bounds__(256) void k_gatherB1(const int* __restrict__ rp2, const int* __restrict__ col,
                                                  const float* __restrict__ dinv, const float* __restrict__ h1,
                                                  const float* __restrict__ tacc, const float* __restrict__ b1,
                                                  float* __restrict__ out1) {
    int t = blockIdx.x * 256 + threadIdx.x;
    int node = t >> 4;
    int c = t & 15;
    int beg = rp2[2 * node + 1], end = rp2[2 * node + 2];
    float acc = 0.f;
    int p = beg;
    for (; p + 1 < end; p += 2) {
        int s0 = col[p], s1 = col[p + 1];
        acc += dinv[s0] * h1[s0 * C1 + c] + dinv[s1] * h1[s1 * C1 + c];
    }
    if (p < end) {
        int s = col[p];
        acc += dinv[s] * h1[s * C1 + c];
    }
    float di = dinv[node];
    float v = di * (acc + tacc[node * C1 + c]) + h1[node * C1 + c] * (di * di) + b1[c];
    out1[node * C1 + c] = fmaxf(v, 0.0f);
}

// pass B for layer 2, fused with W2/b2/relu -> d_out (ppi)
__global__ __launch_bounds__(256) void k_gatherB2(const int* __restrict__ rp2, const int* __restrict__ col,
                                                  const float* __restrict__ dinv, const float* __restrict__ out1,
                                                  const float* __restrict__ tacc,
                                                  const float* __restrict__ W2, const float* __restrict__ b2,
                                                  float* __restrict__ out) {
    __shared__ float sacc[16][17];
    __shared__ float sW[16 * 32];
    __shared__ float sb[32];
    int tid = threadIdx.x;
    if (tid < 128)
        *reinterpret_cast<float4*>(&sW[tid * 4]) = *reinterpret_cast<const float4*>(&W2[tid * 4]);
    if (tid < 32) sb[tid] = b2[tid];
    int g = tid >> 4;
    int c = tid & 15;
    int node = blockIdx.x * 16 + g;
    int beg = rp2[2 * node + 1], end = rp2[2 * node + 2];
    float di = dinv[node];
    float acc = 0.f;
    int p = beg;
    for (; p + 1 < end; p += 2) {
        int s0 = col[p], s1 = col[p + 1];
        acc += dinv[s0] * out1[s0 * C1 + c] + dinv[s1] * out1[s1 * C1 + c];
    }
    if (p < end) {
        int s = col[p];
        acc += dinv[s] * out1[s * C1 + c];
    }
    sacc[g][c] = di * (acc + tacc[node * C1 + c]) + (di * di) * out1[node * C1 + c];
    __syncthreads();
    float r0 = sb[c], r1 = sb[c + 16];
    #pragma unroll
    for (int k = 0; k < 16; ++k) {
        float a = sacc[g][k];
        r0 += a * sW[k * 32 + c];
        r1 += a * sW[k * 32 + c + 16];
    }
    out[node * C2 + c] = fmaxf(r0, 0.f);
    out[node * C2 + c + 16] = fmaxf(r1, 0.f);
}

// ---------------- DDI branch ----------------

#define DDI_CHUNK 132   // 1056 = 8 * 132

__global__ __launch_bounds__(256) void k_ddi(const float* __restrict__ feat,
                                             const float* __restrict__ fW1, const float* __restrict__ fb1,
                                             const float* __restrict__ fW2, const float* __restrict__ fb2,
                                             const float* __restrict__ fW3, const float* __restrict__ fb3,
                                             float* __restrict__ out) {
    __shared__ float sW[DDI_CHUNK * 64];
    __shared__ float sH[4][64];
    int tid = threadIdx.x;
    int wave = tid >> 6;
    int lane = tid & 63;
    int row = blockIdx.x * 4 + wave;

    float acc = 0.f;
    for (int k0 = 0; k0 < F_DDI; k0 += DDI_CHUNK) {
        __syncthreads();
        for (int idx = tid; idx < DDI_CHUNK * 64; idx += 256)
            sW[idx] = fW1[k0 * 64 + idx];
        __syncthreads();
        const float* frow = &feat[(size_t)row * F_DDI + k0];
        #pragma unroll 4
        for (int kk = 0; kk < DDI_CHUNK; kk += 4) {
            float4 fv = *reinterpret_cast<const float4*>(&frow[kk]);
            acc += fv.x * sW[(kk + 0) * 64 + lane];
            acc += fv.y * sW[(kk + 1) * 64 + lane];
            acc += fv.z * sW[(kk + 2) * 64 + lane];
            acc += fv.w * sW[(kk + 3) * 64 + lane];
        }
    }
    float h = fmaxf(acc + fb1[lane], 0.f);
    __syncthreads();
    sH[wave][lane] = h;
    __syncthreads();

    int c16 = lane & 15;
    float acc2 = 0.f;
    #pragma unroll
    for (int kk = 0; kk < 64; ++kk)
        acc2 += sH[wave][kk] * fW2[kk * 16 + c16];
    float o2 = fmaxf(acc2 + fb2[c16], 0.f);
    float part = o2 * fW3[c16];
    #pragma unroll
    for (int off = 8; off >= 1; off >>= 1)
        part += __shfl_xor(part, off, 16);
    if (lane == 0)
        out[row] = fmaxf(part + fb3[0], 0.f);
}

// ---------------- launch ----------------

extern "C" void kernel_launch(void* const* d_in, const int* in_sizes, int n_in,
                              void* d_out, int out_size, void* d_ws, size_t ws_size,
                              hipStream_t stream) {
    const float* x   = (const float*)d_in[0];
    const int*   ei  = (const int*)d_in[1];
    const float* ddi = (const float*)d_in[2];
    const float* W1  = (const float*)d_in[3];
    const float* b1  = (const float*)d_in[4];
    const float* W2  = (const float*)d_in[5];
    const float* b2  = (const float*)d_in[6];
    const float* fW1 = (const float*)d_in[7];
    const float* fb1 = (const float*)d_in[8];
    const float* fW2 = (const float*)d_in[9];
    const float* fb2 = (const float*)d_in[10];
    const float* fW3 = (const float*)d_in[11];
    const float* fb3 = (const float*)d_in[12];

    char* ws = (char*)d_ws;
    float* dinv  = (float*)(ws + O_DINV);
    int*   rp2   = (int*)(ws + O_RP2);
    int*   col   = (int*)(ws + O_COL);
    float* h1    = (float*)(ws + O_H1);
    float* out1  = (float*)(ws + O_OUT1);
    float* tacc  = (float*)(ws + O_TACC);
    int*   bcnt  = (int*)(ws + O_BCNT);
    int*   bbase = (int*)(ws + O_BBASE);
    int*   gcur  = (int*)(ws + O_GCUR);
    unsigned int* gbuf = (unsigned int*)(ws + O_H1);  // alias, dead before h1 written

    float* out_ppi = (float*)d_out;
    float* out_ddi = out_ppi + (size_t)N_NODES * C2;

    hipMemsetAsync(bcnt, 0, NBUCK * sizeof(int), stream);
    k_bcnt<<<NB_BIN, 256, 0, stream>>>(ei, bcnt);
    k_bscan<<<1, 256, 0, stream>>>(bcnt, bbase, gcur, rp2);
    k_bin<<<NB_BIN, 256, 0, stream>>>(ei, gcur, gbuf);
    k_place<<<NBUCK, 512, 0, stream>>>(bbase, gbuf, col, rp2, dinv);

    k_gemm1<<<(N_NODES + 63) / 64, 256, 0, stream>>>(x, W1, h1);

    k_gatherA<<<N_NODES * C1 / 256, 256, 0, stream>>>(rp2, col, dinv, h1, tacc);
    k_gatherB1<<<N_NODES * C1 / 256, 256, 0, stream>>>(rp2, col, dinv, h1, tacc, b1, out1);
    k_gatherA<<<N_NODES * C1 / 256, 256, 0, stream>>>(rp2, col, dinv, out1, tacc);
    k_gatherB2<<<N_NODES / 16, 256, 0, stream>>>(rp2, col, dinv, out1, tacc, W2, b2, out_ppi);

    k_ddi<<<B_DDI / 4, 256, 0, stream>>>(ddi, fW1, fb1, fW2, fb2, fW3, fb3, out_ddi);
}